// Round 16
// baseline (328.710 us; speedup 1.0000x reference)
//
#include <hip/hip_runtime.h>
#include <math.h>

#define N_EL    16
#define N_NUC   4
#define N_FEATS 32
#define N_PAIRS 184
#define HIDDEN  64
#define TB      32           // batch elements per block
#define BLOCK   256
#define H1LD    68           // h1 stride in tail kernel
#define TPW     23           // K-tiles (2 pairs each) per wave; 4*23*2 = 184
#define WS_DIST_OFF 393216                     // dists at 384 KB
#define WS_PART_OFF (393216 + 24117248)        // partials after 24 MB of dists

typedef int   intx8    __attribute__((ext_vector_type(8)));
typedef float floatx16 __attribute__((ext_vector_type(16)));

__device__ __forceinline__ float exp2_raw(float x) {
    float r;
    asm("v_exp_f32 %0, %1" : "=v"(r) : "v"(x));
    return r;
}
__device__ __forceinline__ float log2_raw(float x) {
    float r;
    asm("v_log_f32 %0, %1" : "=v"(r) : "v"(x));
    return r;
}

// triu_indices(16, 1)
__constant__ unsigned char c_I[120] = {
    0,0,0,0,0,0,0,0,0,0,0,0,0,0,0,
    1,1,1,1,1,1,1,1,1,1,1,1,1,1,
    2,2,2,2,2,2,2,2,2,2,2,2,2,
    3,3,3,3,3,3,3,3,3,3,3,3,
    4,4,4,4,4,4,4,4,4,4,4,
    5,5,5,5,5,5,5,5,5,5,
    6,6,6,6,6,6,6,6,6,
    7,7,7,7,7,7,7,7,
    8,8,8,8,8,8,8,
    9,9,9,9,9,9,
    10,10,10,10,10,
    11,11,11,11,
    12,12,12,
    13,13,
    14
};
__constant__ unsigned char c_J[120] = {
    1,2,3,4,5,6,7,8,9,10,11,12,13,14,15,
    2,3,4,5,6,7,8,9,10,11,12,13,14,15,
    3,4,5,6,7,8,9,10,11,12,13,14,15,
    4,5,6,7,8,9,10,11,12,13,14,15,
    5,6,7,8,9,10,11,12,13,14,15,
    6,7,8,9,10,11,12,13,14,15,
    7,8,9,10,11,12,13,14,15,
    8,9,10,11,12,13,14,15,
    9,10,11,12,13,14,15,
    10,11,12,13,14,15,
    11,12,13,14,15,
    12,13,14,15,
    13,14,15,
    14,15,
    15
};

// R16: stable ssp on raw HW transcendentals (replaces OCML log1pf ~30 instrs):
// ssp(x) = max(x,0) + ln2*log2(1 + 2^(-|x|*log2e)) - ln2
__device__ __forceinline__ float ssp(float x) {
    const float z = exp2_raw(-fabsf(x) * 1.4426950408889634f);
    const float w = log2_raw(1.0f + z);
    return fmaxf(x, 0.0f) + fmaf(0.6931471805599453f, w, -0.69314718056f);
}
__device__ __forceinline__ float redg(float v) {
    v += __shfl_xor(v, 1);
    v += __shfl_xor(v, 2);
    v += __shfl_xor(v, 4);
    return v;
}

// ---------------------------------------------------------------------------
// Prep (verified R14): W1 -> fp8 e4m3 (pre-scaled 2^6; MFMA applies 2^-6 via
// scale_b) in 32x32x64 B-fragment order.
// ---------------------------------------------------------------------------
__global__ __launch_bounds__(256)
void prep_w1_kernel(const float* __restrict__ W1, intx8* __restrict__ ws)
{
    __shared__ float w[2 * N_FEATS * HIDDEN];
    const int t = blockIdx.x;
    const float* src = W1 + (size_t)(2 * t) * (N_FEATS * HIDDEN);
    for (int k = threadIdx.x; k < 2 * N_FEATS * HIDDEN; k += 256) w[k] = src[k];
    __syncthreads();

    const int tid = threadIdx.x;
    if (tid >= 128) return;
    const int lane = tid & 63;
    const int nh   = tid >> 6;
    const int lh   = lane >> 5;
    const int col  = nh * 32 + (lane & 31);
    const int fb   = lh * 16;
    intx8 frag;
#pragma unroll
    for (int r = 0; r < 8; ++r) {
        const int pair = r >> 2;
        const int fo   = fb + ((r & 3) << 2);
        const float v0 = 64.0f * w[(pair * N_FEATS + fo + 0) * 64 + col];
        const float v1 = 64.0f * w[(pair * N_FEATS + fo + 1) * 64 + col];
        const float v2 = 64.0f * w[(pair * N_FEATS + fo + 2) * 64 + col];
        const float v3 = 64.0f * w[(pair * N_FEATS + fo + 3) * 64 + col];
        int d = __builtin_amdgcn_cvt_pk_fp8_f32(v0, v1, 0, false);
        d     = __builtin_amdgcn_cvt_pk_fp8_f32(v2, v3, d, true);
        frag[r] = d;
    }
    ws[(size_t)(t * 2 + nh) * 64 + lane] = frag;
}

// ---------------------------------------------------------------------------
// Dist kernel (new in R16): all 184 distances per element -> global dw in
// the exact layout the gemm reads: dw[b*5888 + p*32 + el] (coalesced both
// ways). Removes ALL LDS from the gemm kernel.
// ---------------------------------------------------------------------------
__global__ __launch_bounds__(256)
void dist_kernel(const float* __restrict__ rs,
                 const float* __restrict__ coords,
                 float* __restrict__ dw)
{
    __shared__ float lds_rs[TB * N_EL * 3];   // 6 KB
    const int tid = threadIdx.x;
    {
        const float* rs_blk = rs + (size_t)blockIdx.x * (TB * N_EL * 3);
        for (int k = tid; k < TB * N_EL * 3; k += 256) lds_rs[k] = rs_blk[k];
    }
    __syncthreads();

    const int el = tid & 31, g = tid >> 5;    // 32 els x 8 pair-groups
    const float* myrs = lds_rs + el * (N_EL * 3);
    float* base = dw + (size_t)blockIdx.x * (N_PAIRS * 32) + el;
#pragma unroll
    for (int i = 0; i < 23; ++i) {            // p = g + 8*i covers 0..183
        const int p = g + 8 * i;
        float dx, dy, dz;
        if (p < 64) {
            const int e = p >> 2, n = p & 3;
            dx = myrs[e * 3 + 0] - coords[n * 3 + 0];
            dy = myrs[e * 3 + 1] - coords[n * 3 + 1];
            dz = myrs[e * 3 + 2] - coords[n * 3 + 2];
        } else {
            const int q  = p - 64;
            const int ei = 3 * (int)c_I[q], ej = 3 * (int)c_J[q];
            dx = myrs[ei + 0] - myrs[ej + 0];
            dy = myrs[ei + 1] - myrs[ej + 1];
            dz = myrs[ei + 2] - myrs[ej + 2];
        }
        base[p * 32] = sqrtf(dx * dx + dy * dy + dz * dz);
    }
}

// ---------------------------------------------------------------------------
// GEMM kernel — ZERO LDS, ZERO barriers (R16). R15 decode: LDS 30 KB capped
// residency at 2 blocks/CU (~64 KB schedulable LDS/CU); occupancy is the only
// lever that has ever moved the wall. Dists stream from dw, B-frags from ws,
// partials dumped raw to global. __launch_bounds__(256,6): 6 waves/EU.
// ---------------------------------------------------------------------------
__global__ __launch_bounds__(BLOCK, 6)
void wfnet_gemm(const float* __restrict__ dw,
                const intx8* __restrict__ ws,
                float* __restrict__ partials)
{
    const int tid  = threadIdx.x;
    const int wave = tid >> 6;
    const int lane = tid & 63;
    const int m    = lane & 31;
    const int lh   = lane >> 5;

    const int f0 = lh * 16;
#define MKC(P, FF) float P##1, P##0; { \
    const float fq = (float)(FF) * (1.0f / 31.0f); \
    const float mu = 10.0f * fq * fq; \
    const float is = 7.0f / (1.0f + 10.0f * fq); \
    P##1 = is * 1.2011224087864498f; \
    P##0 = -mu * P##1; }
    MKC(F0_,  f0 + 0)  MKC(F1_,  f0 + 1)  MKC(F2_,  f0 + 2)  MKC(F3_,  f0 + 3)
    MKC(F4_,  f0 + 4)  MKC(F5_,  f0 + 5)  MKC(F6_,  f0 + 6)  MKC(F7_,  f0 + 7)
    MKC(F8_,  f0 + 8)  MKC(F9_,  f0 + 9)  MKC(F10_, f0 + 10) MKC(F11_, f0 + 11)
    MKC(F12_, f0 + 12) MKC(F13_, f0 + 13) MKC(F14_, f0 + 14) MKC(F15_, f0 + 15)
#undef MKC

    floatx16 accA = {};
    floatx16 accB = {};
    const intx8* wq = ws + ((size_t)(wave * TPW) * 128 + lane);
    const float* dp = dw + (size_t)blockIdx.x * (N_PAIRS * 32)
                         + (wave * 2 * TPW) * 32 + m;

#define XO(dd, P) ({ const float t_ = fmaf(dd, P##1, P##0); exp2_raw(t_ * -t_); })
#define MKA8(AV, dx0, dx1) \
    intx8 AV; { int dw_; \
    dw_   = __builtin_amdgcn_cvt_pk_fp8_f32(XO(dx0,F0_),  XO(dx0,F1_),  0,  false); \
    AV[0] = __builtin_amdgcn_cvt_pk_fp8_f32(XO(dx0,F2_),  XO(dx0,F3_),  dw_, true); \
    dw_   = __builtin_amdgcn_cvt_pk_fp8_f32(XO(dx0,F4_),  XO(dx0,F5_),  0,  false); \
    AV[1] = __builtin_amdgcn_cvt_pk_fp8_f32(XO(dx0,F6_),  XO(dx0,F7_),  dw_, true); \
    dw_   = __builtin_amdgcn_cvt_pk_fp8_f32(XO(dx0,F8_),  XO(dx0,F9_),  0,  false); \
    AV[2] = __builtin_amdgcn_cvt_pk_fp8_f32(XO(dx0,F10_), XO(dx0,F11_), dw_, true); \
    dw_   = __builtin_amdgcn_cvt_pk_fp8_f32(XO(dx0,F12_), XO(dx0,F13_), 0,  false); \
    AV[3] = __builtin_amdgcn_cvt_pk_fp8_f32(XO(dx0,F14_), XO(dx0,F15_), dw_, true); \
    dw_   = __builtin_amdgcn_cvt_pk_fp8_f32(XO(dx1,F0_),  XO(dx1,F1_),  0,  false); \
    AV[4] = __builtin_amdgcn_cvt_pk_fp8_f32(XO(dx1,F2_),  XO(dx1,F3_),  dw_, true); \
    dw_   = __builtin_amdgcn_cvt_pk_fp8_f32(XO(dx1,F4_),  XO(dx1,F5_),  0,  false); \
    AV[5] = __builtin_amdgcn_cvt_pk_fp8_f32(XO(dx1,F6_),  XO(dx1,F7_),  dw_, true); \
    dw_   = __builtin_amdgcn_cvt_pk_fp8_f32(XO(dx1,F8_),  XO(dx1,F9_),  0,  false); \
    AV[6] = __builtin_amdgcn_cvt_pk_fp8_f32(XO(dx1,F10_), XO(dx1,F11_), dw_, true); \
    dw_   = __builtin_amdgcn_cvt_pk_fp8_f32(XO(dx1,F12_), XO(dx1,F13_), 0,  false); \
    AV[7] = __builtin_amdgcn_cvt_pk_fp8_f32(XO(dx1,F14_), XO(dx1,F15_), dw_, true); }
#define KROUND(AV, Q0, Q1) { \
    accA = __builtin_amdgcn_mfma_scale_f32_32x32x64_f8f6f4( \
               AV, Q0, accA, 0, 0, 0, 0x7F7F7F7F, 0, 0x79797979); \
    accB = __builtin_amdgcn_mfma_scale_f32_32x32x64_f8f6f4( \
               AV, Q1, accB, 0, 0, 0, 0x7F7F7F7F, 0, 0x79797979); }

    intx8 pA0 = wq[0],   pA1 = wq[64];
    intx8 pB0 = wq[128], pB1 = wq[192];
    float dA0 = dp[0],  dA1 = dp[32];
    float dB0 = dp[64], dB1 = dp[96];

    for (int it = 0; it < 10; ++it) {
        const intx8* wn = wq + 256;
        const float* dn = dp + 128;
        const float eA0 = dn[0],  eA1 = dn[32];
        const float eB0 = dn[64], eB1 = dn[96];

        { MKA8(av, dA0, dA1) KROUND(av, pA0, pA1) }
        pA0 = wn[0]; pA1 = wn[64];

        { MKA8(bv, dB0, dB1) KROUND(bv, pB0, pB1) }
        pB0 = wn[128]; pB1 = wn[192];

        wq = wn; dp = dn;
        dA0 = eA0; dA1 = eA1; dB0 = eB0; dB1 = eB1;
    }
    {   // rounds 20, 21, 22 (pairs 40..45; dp now at pair 40)
        const intx8* wn = wq + 256;
        const float eA0 = dp[128], eA1 = dp[160];   // pairs 44, 45
        { MKA8(av, dA0, dA1) KROUND(av, pA0, pA1) }
        pA0 = wn[0]; pA1 = wn[64];
        { MKA8(bv, dB0, dB1) KROUND(bv, pB0, pB1) }
        { MKA8(cv, eA0, eA1) KROUND(cv, pA0, pA1) }
    }
#undef KROUND
#undef MKA8
#undef XO

    // dump raw partial. C/D: col = lane&31 (+32), row el = (rg&3)+8*(rg>>2)+4*lh
    float* pdst = partials + ((size_t)blockIdx.x * 4 + wave) * 2048;
#pragma unroll
    for (int rg = 0; rg < 16; ++rg) {
        const int el = (rg & 3) + 8 * (rg >> 2) + 4 * lh;
        pdst[el * 64 + m]      = accA[rg];
        pdst[el * 64 + 32 + m] = accB[rg];
    }
}

// ---------------------------------------------------------------------------
// Tail (R15 structure + fast ssp): sum 4 partials + b1 + ssp -> h1 (LDS) ->
// layers 2/3 + asy + output. 14.7 KB LDS -> 4 blocks/CU.
// ---------------------------------------------------------------------------
__global__ __launch_bounds__(BLOCK)
void wfnet_tail(const float* __restrict__ rs,
                const float* __restrict__ coords,
                const float* __restrict__ charges,
                const float* __restrict__ partials,
                const float* __restrict__ b1,
                const float* __restrict__ W2,
                const float* __restrict__ b2,
                const float* __restrict__ W3,
                const float* __restrict__ b3,
                float* __restrict__ out)
{
    __shared__ float lds_rs[TB * N_EL * 3];   // 6 KB
    __shared__ float lds_h1[TB * H1LD];       // 8.7 KB

    const int tid = threadIdx.x;
    const int el  = tid >> 3;
    const int g   = tid & 7;
    const int b   = blockIdx.x * TB + el;

    {
        const float* rs_blk = rs + (size_t)blockIdx.x * (TB * N_EL * 3);
        for (int k = tid; k < TB * N_EL * 3; k += BLOCK) lds_rs[k] = rs_blk[k];
    }

    {
        const float* pb = partials + (size_t)blockIdx.x * 8192 + el * 64 + g * 8;
        const float4 p00 = ((const float4*)(pb + 0 * 2048))[0];
        const float4 p01 = ((const float4*)(pb + 0 * 2048))[1];
        const float4 p10 = ((const float4*)(pb + 1 * 2048))[0];
        const float4 p11 = ((const float4*)(pb + 1 * 2048))[1];
        const float4 p20 = ((const float4*)(pb + 2 * 2048))[0];
        const float4 p21 = ((const float4*)(pb + 2 * 2048))[1];
        const float4 p30 = ((const float4*)(pb + 3 * 2048))[0];
        const float4 p31 = ((const float4*)(pb + 3 * 2048))[1];
        const float4 ba = ((const float4*)(b1 + g * 8))[0];
        const float4 bb = ((const float4*)(b1 + g * 8))[1];
        float* h1w = lds_h1 + el * H1LD + g * 8;
        h1w[0] = ssp(p00.x + p10.x + p20.x + p30.x + ba.x);
        h1w[1] = ssp(p00.y + p10.y + p20.y + p30.y + ba.y);
        h1w[2] = ssp(p00.z + p10.z + p20.z + p30.z + ba.z);
        h1w[3] = ssp(p00.w + p10.w + p20.w + p30.w + ba.w);
        h1w[4] = ssp(p01.x + p11.x + p21.x + p31.x + bb.x);
        h1w[5] = ssp(p01.y + p11.y + p21.y + p31.y + bb.y);
        h1w[6] = ssp(p01.z + p11.z + p21.z + p31.z + bb.z);
        h1w[7] = ssp(p01.w + p11.w + p21.w + p31.w + bb.w);
    }

    float asy = 0.0f;
    __syncthreads();
    {
        const float* myrs = lds_rs + el * (N_EL * 3);
        const float4 ch = *(const float4*)charges;
#pragma unroll
        for (int i = 0; i < 8; ++i) {
            const int p = g + 8 * i;
            const int e = p >> 2, n = p & 3;
            const float dx = myrs[e * 3 + 0] - coords[n * 3 + 0];
            const float dy = myrs[e * 3 + 1] - coords[n * 3 + 1];
            const float dz = myrs[e * 3 + 2] - coords[n * 3 + 2];
            const float d = sqrtf(dx * dx + dy * dy + dz * dz);
            const float Z = (n < 2) ? ((n == 0) ? ch.x : ch.y)
                                    : ((n == 2) ? ch.z : ch.w);
            asy += (Z * d + d * d) / (1.0f + d);   // decay = sqrt(2*0.5) = 1
        }
    }
    asy = redg(asy);

    const float4* __restrict__ W2v = (const float4*)W2;
    const float4* __restrict__ b2v = (const float4*)b2;
    const int wbi = g * 2;
    const float4 b2a = b2v[wbi], b2b = b2v[wbi + 1];
    float s0 = b2a.x, s1 = b2a.y, s2 = b2a.z, s3 = b2a.w;
    float s4 = b2b.x, s5 = b2b.y, s6 = b2b.z, s7 = b2b.w;

    const float* __restrict__ h1row = lds_h1 + el * H1LD;
    for (int k = 0; k < HIDDEN; ++k) {
        const float hk  = h1row[k];
        const float4 wa = W2v[k * 16 + wbi];
        const float4 wb = W2v[k * 16 + wbi + 1];
        s0 = fmaf(hk, wa.x, s0); s1 = fmaf(hk, wa.y, s1);
        s2 = fmaf(hk, wa.z, s2); s3 = fmaf(hk, wa.w, s3);
        s4 = fmaf(hk, wb.x, s4); s5 = fmaf(hk, wb.y, s5);
        s6 = fmaf(hk, wb.z, s6); s7 = fmaf(hk, wb.w, s7);
    }

    const float4* __restrict__ W3v = (const float4*)W3;
    const float4 w3a = W3v[wbi], w3b = W3v[wbi + 1];
    float part = ssp(s0) * w3a.x + ssp(s1) * w3a.y
               + ssp(s2) * w3a.z + ssp(s3) * w3a.w
               + ssp(s4) * w3b.x + ssp(s5) * w3b.y
               + ssp(s6) * w3b.z + ssp(s7) * w3b.w;
    part = redg(part);

    if (g == 0) {
        const float ys = part + b3[0];
        out[b] = __expf(ys) * __expf(-asy);
    }
}

extern "C" void kernel_launch(void* const* d_in, const int* in_sizes, int n_in,
                              void* d_out, int out_size, void* d_ws, size_t ws_size,
                              hipStream_t stream) {
    const float* rs      = (const float*)d_in[0];
    const float* coords  = (const float*)d_in[1];
    const float* charges = (const float*)d_in[2];
    const float* W1      = (const float*)d_in[3];
    const float* b1      = (const float*)d_in[4];
    const float* W2      = (const float*)d_in[5];
    const float* b2      = (const float*)d_in[6];
    const float* W3      = (const float*)d_in[7];
    const float* b3      = (const float*)d_in[8];
    float* out = (float*)d_out;

    const int batch = in_sizes[0] / (N_EL * 3);   // 32768
    intx8* w1f8     = (intx8*)d_ws;                          // 368 KB
    float* dists    = (float*)((char*)d_ws + WS_DIST_OFF);   // 24 MB
    float* partials = (float*)((char*)d_ws + WS_PART_OFF);   // 32 MB

    prep_w1_kernel<<<N_PAIRS / 2, 256, 0, stream>>>(W1, w1f8);
    dist_kernel<<<batch / TB, 256, 0, stream>>>(rs, coords, dists);
    wfnet_gemm<<<batch / TB, BLOCK, 0, stream>>>(dists, w1f8, partials);
    wfnet_tail<<<batch / TB, BLOCK, 0, stream>>>(rs, coords, charges, partials,
                                                 b1, W2, b2, W3, b3, out);
}

// Round 17
// 166.116 us; speedup vs baseline: 1.9788x; 1.9788x over previous
//
#include <hip/hip_runtime.h>
#include <math.h>

#define N_EL    16
#define N_NUC   4
#define N_FEATS 32
#define N_PAIRS 184
#define HIDDEN  64
#define TB      32           // batch elements per block
#define BLOCK   256
#define H1LD    68           // h1 stride in tail kernel
#define TPW     23           // K-tiles (2 pairs each) per wave; 4*23*2 = 184
#define WS_DIST_OFF 393216                     // dists at 384 KB
#define WS_PART_OFF (393216 + 24117248)        // partials after 24 MB of dists

typedef int   intx8    __attribute__((ext_vector_type(8)));
typedef float floatx16 __attribute__((ext_vector_type(16)));

__device__ __forceinline__ float exp2_raw(float x) {
    float r;
    asm("v_exp_f32 %0, %1" : "=v"(r) : "v"(x));
    return r;
}
__device__ __forceinline__ float log2_raw(float x) {
    float r;
    asm("v_log_f32 %0, %1" : "=v"(r) : "v"(x));
    return r;
}

// triu_indices(16, 1)
__constant__ unsigned char c_I[120] = {
    0,0,0,0,0,0,0,0,0,0,0,0,0,0,0,
    1,1,1,1,1,1,1,1,1,1,1,1,1,1,
    2,2,2,2,2,2,2,2,2,2,2,2,2,
    3,3,3,3,3,3,3,3,3,3,3,3,
    4,4,4,4,4,4,4,4,4,4,4,
    5,5,5,5,5,5,5,5,5,5,
    6,6,6,6,6,6,6,6,6,
    7,7,7,7,7,7,7,7,
    8,8,8,8,8,8,8,
    9,9,9,9,9,9,
    10,10,10,10,10,
    11,11,11,11,
    12,12,12,
    13,13,
    14
};
__constant__ unsigned char c_J[120] = {
    1,2,3,4,5,6,7,8,9,10,11,12,13,14,15,
    2,3,4,5,6,7,8,9,10,11,12,13,14,15,
    3,4,5,6,7,8,9,10,11,12,13,14,15,
    4,5,6,7,8,9,10,11,12,13,14,15,
    5,6,7,8,9,10,11,12,13,14,15,
    6,7,8,9,10,11,12,13,14,15,
    7,8,9,10,11,12,13,14,15,
    8,9,10,11,12,13,14,15,
    9,10,11,12,13,14,15,
    10,11,12,13,14,15,
    11,12,13,14,15,
    12,13,14,15,
    13,14,15,
    14,15,
    15
};

// stable ssp on raw HW transcendentals:
// ssp(x) = max(x,0) + ln2*log2(1 + 2^(-|x|*log2e)) - ln2
__device__ __forceinline__ float ssp(float x) {
    const float z = exp2_raw(-fabsf(x) * 1.4426950408889634f);
    const float w = log2_raw(1.0f + z);
    return fmaxf(x, 0.0f) + fmaf(0.6931471805599453f, w, -0.69314718056f);
}
__device__ __forceinline__ float redg(float v) {
    v += __shfl_xor(v, 1);
    v += __shfl_xor(v, 2);
    v += __shfl_xor(v, 4);
    return v;
}

// ---------------------------------------------------------------------------
// Prep (verified R14): W1 -> fp8 e4m3 (pre-scaled 2^6; MFMA applies 2^-6 via
// scale_b) in 32x32x64 B-fragment order.
// ---------------------------------------------------------------------------
__global__ __launch_bounds__(256)
void prep_w1_kernel(const float* __restrict__ W1, intx8* __restrict__ ws)
{
    __shared__ float w[2 * N_FEATS * HIDDEN];
    const int t = blockIdx.x;
    const float* src = W1 + (size_t)(2 * t) * (N_FEATS * HIDDEN);
    for (int k = threadIdx.x; k < 2 * N_FEATS * HIDDEN; k += 256) w[k] = src[k];
    __syncthreads();

    const int tid = threadIdx.x;
    if (tid >= 128) return;
    const int lane = tid & 63;
    const int nh   = tid >> 6;
    const int lh   = lane >> 5;
    const int col  = nh * 32 + (lane & 31);
    const int fb   = lh * 16;
    intx8 frag;
#pragma unroll
    for (int r = 0; r < 8; ++r) {
        const int pair = r >> 2;
        const int fo   = fb + ((r & 3) << 2);
        const float v0 = 64.0f * w[(pair * N_FEATS + fo + 0) * 64 + col];
        const float v1 = 64.0f * w[(pair * N_FEATS + fo + 1) * 64 + col];
        const float v2 = 64.0f * w[(pair * N_FEATS + fo + 2) * 64 + col];
        const float v3 = 64.0f * w[(pair * N_FEATS + fo + 3) * 64 + col];
        int d = __builtin_amdgcn_cvt_pk_fp8_f32(v0, v1, 0, false);
        d     = __builtin_amdgcn_cvt_pk_fp8_f32(v2, v3, d, true);
        frag[r] = d;
    }
    ws[(size_t)(t * 2 + nh) * 64 + lane] = frag;
}

// ---------------------------------------------------------------------------
// Dist kernel (R16): all 184 distances per element -> global dw in the exact
// layout the gemm reads: dw[b*5888 + p*32 + el].
// ---------------------------------------------------------------------------
__global__ __launch_bounds__(256)
void dist_kernel(const float* __restrict__ rs,
                 const float* __restrict__ coords,
                 float* __restrict__ dw)
{
    __shared__ float lds_rs[TB * N_EL * 3];   // 6 KB
    const int tid = threadIdx.x;
    {
        const float* rs_blk = rs + (size_t)blockIdx.x * (TB * N_EL * 3);
        for (int k = tid; k < TB * N_EL * 3; k += 256) lds_rs[k] = rs_blk[k];
    }
    __syncthreads();

    const int el = tid & 31, g = tid >> 5;    // 32 els x 8 pair-groups
    const float* myrs = lds_rs + el * (N_EL * 3);
    float* base = dw + (size_t)blockIdx.x * (N_PAIRS * 32) + el;
#pragma unroll
    for (int i = 0; i < 23; ++i) {            // p = g + 8*i covers 0..183
        const int p = g + 8 * i;
        float dx, dy, dz;
        if (p < 64) {
            const int e = p >> 2, n = p & 3;
            dx = myrs[e * 3 + 0] - coords[n * 3 + 0];
            dy = myrs[e * 3 + 1] - coords[n * 3 + 1];
            dz = myrs[e * 3 + 2] - coords[n * 3 + 2];
        } else {
            const int q  = p - 64;
            const int ei = 3 * (int)c_I[q], ej = 3 * (int)c_J[q];
            dx = myrs[ei + 0] - myrs[ej + 0];
            dy = myrs[ei + 1] - myrs[ej + 1];
            dz = myrs[ei + 2] - myrs[ej + 2];
        }
        base[p * 32] = sqrtf(dx * dx + dy * dy + dz * dz);
    }
}

// ---------------------------------------------------------------------------
// GEMM kernel — ZERO LDS, ZERO barriers. R16 post-mortem: launch_bounds
// (256,6) set an ~85-VGPR budget -> allocator squeezed to 40 and SPILLED THE
// ACCUMULATORS (WRITE_SIZE 541 MB, 204 us). (256,4) gives a 128-reg budget;
// live set ~112 fits. Zero LDS -> VGPR-bound 16 waves/CU (2x the R15 TLP).
// ---------------------------------------------------------------------------
__global__ __launch_bounds__(BLOCK, 4)
void wfnet_gemm(const float* __restrict__ dw,
                const intx8* __restrict__ ws,
                float* __restrict__ partials)
{
    const int tid  = threadIdx.x;
    const int wave = tid >> 6;
    const int lane = tid & 63;
    const int m    = lane & 31;
    const int lh   = lane >> 5;

    const int f0 = lh * 16;
#define MKC(P, FF) float P##1, P##0; { \
    const float fq = (float)(FF) * (1.0f / 31.0f); \
    const float mu = 10.0f * fq * fq; \
    const float is = 7.0f / (1.0f + 10.0f * fq); \
    P##1 = is * 1.2011224087864498f; \
    P##0 = -mu * P##1; }
    MKC(F0_,  f0 + 0)  MKC(F1_,  f0 + 1)  MKC(F2_,  f0 + 2)  MKC(F3_,  f0 + 3)
    MKC(F4_,  f0 + 4)  MKC(F5_,  f0 + 5)  MKC(F6_,  f0 + 6)  MKC(F7_,  f0 + 7)
    MKC(F8_,  f0 + 8)  MKC(F9_,  f0 + 9)  MKC(F10_, f0 + 10) MKC(F11_, f0 + 11)
    MKC(F12_, f0 + 12) MKC(F13_, f0 + 13) MKC(F14_, f0 + 14) MKC(F15_, f0 + 15)
#undef MKC

    floatx16 accA = {};
    floatx16 accB = {};
    const intx8* wq = ws + ((size_t)(wave * TPW) * 128 + lane);
    const float* dp = dw + (size_t)blockIdx.x * (N_PAIRS * 32)
                         + (wave * 2 * TPW) * 32 + m;

#define XO(dd, P) ({ const float t_ = fmaf(dd, P##1, P##0); exp2_raw(t_ * -t_); })
#define MKA8(AV, dx0, dx1) \
    intx8 AV; { int dw_; \
    dw_   = __builtin_amdgcn_cvt_pk_fp8_f32(XO(dx0,F0_),  XO(dx0,F1_),  0,  false); \
    AV[0] = __builtin_amdgcn_cvt_pk_fp8_f32(XO(dx0,F2_),  XO(dx0,F3_),  dw_, true); \
    dw_   = __builtin_amdgcn_cvt_pk_fp8_f32(XO(dx0,F4_),  XO(dx0,F5_),  0,  false); \
    AV[1] = __builtin_amdgcn_cvt_pk_fp8_f32(XO(dx0,F6_),  XO(dx0,F7_),  dw_, true); \
    dw_   = __builtin_amdgcn_cvt_pk_fp8_f32(XO(dx0,F8_),  XO(dx0,F9_),  0,  false); \
    AV[2] = __builtin_amdgcn_cvt_pk_fp8_f32(XO(dx0,F10_), XO(dx0,F11_), dw_, true); \
    dw_   = __builtin_amdgcn_cvt_pk_fp8_f32(XO(dx0,F12_), XO(dx0,F13_), 0,  false); \
    AV[3] = __builtin_amdgcn_cvt_pk_fp8_f32(XO(dx0,F14_), XO(dx0,F15_), dw_, true); \
    dw_   = __builtin_amdgcn_cvt_pk_fp8_f32(XO(dx1,F0_),  XO(dx1,F1_),  0,  false); \
    AV[4] = __builtin_amdgcn_cvt_pk_fp8_f32(XO(dx1,F2_),  XO(dx1,F3_),  dw_, true); \
    dw_   = __builtin_amdgcn_cvt_pk_fp8_f32(XO(dx1,F4_),  XO(dx1,F5_),  0,  false); \
    AV[5] = __builtin_amdgcn_cvt_pk_fp8_f32(XO(dx1,F6_),  XO(dx1,F7_),  dw_, true); \
    dw_   = __builtin_amdgcn_cvt_pk_fp8_f32(XO(dx1,F8_),  XO(dx1,F9_),  0,  false); \
    AV[6] = __builtin_amdgcn_cvt_pk_fp8_f32(XO(dx1,F10_), XO(dx1,F11_), dw_, true); \
    dw_   = __builtin_amdgcn_cvt_pk_fp8_f32(XO(dx1,F12_), XO(dx1,F13_), 0,  false); \
    AV[7] = __builtin_amdgcn_cvt_pk_fp8_f32(XO(dx1,F14_), XO(dx1,F15_), dw_, true); }
#define KROUND(AV, Q0, Q1) { \
    accA = __builtin_amdgcn_mfma_scale_f32_32x32x64_f8f6f4( \
               AV, Q0, accA, 0, 0, 0, 0x7F7F7F7F, 0, 0x79797979); \
    accB = __builtin_amdgcn_mfma_scale_f32_32x32x64_f8f6f4( \
               AV, Q1, accB, 0, 0, 0, 0x7F7F7F7F, 0, 0x79797979); }

    intx8 pA0 = wq[0],   pA1 = wq[64];
    intx8 pB0 = wq[128], pB1 = wq[192];
    float dA0 = dp[0],  dA1 = dp[32];
    float dB0 = dp[64], dB1 = dp[96];

    for (int it = 0; it < 10; ++it) {
        const intx8* wn = wq + 256;
        const float* dn = dp + 128;
        const float eA0 = dn[0],  eA1 = dn[32];
        const float eB0 = dn[64], eB1 = dn[96];

        { MKA8(av, dA0, dA1) KROUND(av, pA0, pA1) }
        pA0 = wn[0]; pA1 = wn[64];

        { MKA8(bv, dB0, dB1) KROUND(bv, pB0, pB1) }
        pB0 = wn[128]; pB1 = wn[192];

        wq = wn; dp = dn;
        dA0 = eA0; dA1 = eA1; dB0 = eB0; dB1 = eB1;
    }
    {   // rounds 20, 21, 22 (pairs 40..45; dp now at pair 40)
        const intx8* wn = wq + 256;
        const float eA0 = dp[128], eA1 = dp[160];   // pairs 44, 45
        { MKA8(av, dA0, dA1) KROUND(av, pA0, pA1) }
        pA0 = wn[0]; pA1 = wn[64];
        { MKA8(bv, dB0, dB1) KROUND(bv, pB0, pB1) }
        { MKA8(cv, eA0, eA1) KROUND(cv, pA0, pA1) }
    }
#undef KROUND
#undef MKA8
#undef XO

    // dump raw partial. C/D: col = lane&31 (+32), row el = (rg&3)+8*(rg>>2)+4*lh
    float* pdst = partials + ((size_t)blockIdx.x * 4 + wave) * 2048;
#pragma unroll
    for (int rg = 0; rg < 16; ++rg) {
        const int el = (rg & 3) + 8 * (rg >> 2) + 4 * lh;
        pdst[el * 64 + m]      = accA[rg];
        pdst[el * 64 + 32 + m] = accB[rg];
    }
}

// ---------------------------------------------------------------------------
// Tail (R15 structure + fast ssp): sum 4 partials + b1 + ssp -> h1 (LDS) ->
// layers 2/3 + asy + output.
// ---------------------------------------------------------------------------
__global__ __launch_bounds__(BLOCK)
void wfnet_tail(const float* __restrict__ rs,
                const float* __restrict__ coords,
                const float* __restrict__ charges,
                const float* __restrict__ partials,
                const float* __restrict__ b1,
                const float* __restrict__ W2,
                const float* __restrict__ b2,
                const float* __restrict__ W3,
                const float* __restrict__ b3,
                float* __restrict__ out)
{
    __shared__ float lds_rs[TB * N_EL * 3];   // 6 KB
    __shared__ float lds_h1[TB * H1LD];       // 8.7 KB

    const int tid = threadIdx.x;
    const int el  = tid >> 3;
    const int g   = tid & 7;
    const int b   = blockIdx.x * TB + el;

    {
        const float* rs_blk = rs + (size_t)blockIdx.x * (TB * N_EL * 3);
        for (int k = tid; k < TB * N_EL * 3; k += BLOCK) lds_rs[k] = rs_blk[k];
    }

    {
        const float* pb = partials + (size_t)blockIdx.x * 8192 + el * 64 + g * 8;
        const float4 p00 = ((const float4*)(pb + 0 * 2048))[0];
        const float4 p01 = ((const float4*)(pb + 0 * 2048))[1];
        const float4 p10 = ((const float4*)(pb + 1 * 2048))[0];
        const float4 p11 = ((const float4*)(pb + 1 * 2048))[1];
        const float4 p20 = ((const float4*)(pb + 2 * 2048))[0];
        const float4 p21 = ((const float4*)(pb + 2 * 2048))[1];
        const float4 p30 = ((const float4*)(pb + 3 * 2048))[0];
        const float4 p31 = ((const float4*)(pb + 3 * 2048))[1];
        const float4 ba = ((const float4*)(b1 + g * 8))[0];
        const float4 bb = ((const float4*)(b1 + g * 8))[1];
        float* h1w = lds_h1 + el * H1LD + g * 8;
        h1w[0] = ssp(p00.x + p10.x + p20.x + p30.x + ba.x);
        h1w[1] = ssp(p00.y + p10.y + p20.y + p30.y + ba.y);
        h1w[2] = ssp(p00.z + p10.z + p20.z + p30.z + ba.z);
        h1w[3] = ssp(p00.w + p10.w + p20.w + p30.w + ba.w);
        h1w[4] = ssp(p01.x + p11.x + p21.x + p31.x + bb.x);
        h1w[5] = ssp(p01.y + p11.y + p21.y + p31.y + bb.y);
        h1w[6] = ssp(p01.z + p11.z + p21.z + p31.z + bb.z);
        h1w[7] = ssp(p01.w + p11.w + p21.w + p31.w + bb.w);
    }

    float asy = 0.0f;
    __syncthreads();
    {
        const float* myrs = lds_rs + el * (N_EL * 3);
        const float4 ch = *(const float4*)charges;
#pragma unroll
        for (int i = 0; i < 8; ++i) {
            const int p = g + 8 * i;
            const int e = p >> 2, n = p & 3;
            const float dx = myrs[e * 3 + 0] - coords[n * 3 + 0];
            const float dy = myrs[e * 3 + 1] - coords[n * 3 + 1];
            const float dz = myrs[e * 3 + 2] - coords[n * 3 + 2];
            const float d = sqrtf(dx * dx + dy * dy + dz * dz);
            const float Z = (n < 2) ? ((n == 0) ? ch.x : ch.y)
                                    : ((n == 2) ? ch.z : ch.w);
            asy += (Z * d + d * d) / (1.0f + d);   // decay = sqrt(2*0.5) = 1
        }
    }
    asy = redg(asy);

    const float4* __restrict__ W2v = (const float4*)W2;
    const float4* __restrict__ b2v = (const float4*)b2;
    const int wbi = g * 2;
    const float4 b2a = b2v[wbi], b2b = b2v[wbi + 1];
    float s0 = b2a.x, s1 = b2a.y, s2 = b2a.z, s3 = b2a.w;
    float s4 = b2b.x, s5 = b2b.y, s6 = b2b.z, s7 = b2b.w;

    const float* __restrict__ h1row = lds_h1 + el * H1LD;
    for (int k = 0; k < HIDDEN; ++k) {
        const float hk  = h1row[k];
        const float4 wa = W2v[k * 16 + wbi];
        const float4 wb = W2v[k * 16 + wbi + 1];
        s0 = fmaf(hk, wa.x, s0); s1 = fmaf(hk, wa.y, s1);
        s2 = fmaf(hk, wa.z, s2); s3 = fmaf(hk, wa.w, s3);
        s4 = fmaf(hk, wb.x, s4); s5 = fmaf(hk, wb.y, s5);
        s6 = fmaf(hk, wb.z, s6); s7 = fmaf(hk, wb.w, s7);
    }

    const float4* __restrict__ W3v = (const float4*)W3;
    const float4 w3a = W3v[wbi], w3b = W3v[wbi + 1];
    float part = ssp(s0) * w3a.x + ssp(s1) * w3a.y
               + ssp(s2) * w3a.z + ssp(s3) * w3a.w
               + ssp(s4) * w3b.x + ssp(s5) * w3b.y
               + ssp(s6) * w3b.z + ssp(s7) * w3b.w;
    part = redg(part);

    if (g == 0) {
        const float ys = part + b3[0];
        out[b] = __expf(ys) * __expf(-asy);
    }
}

extern "C" void kernel_launch(void* const* d_in, const int* in_sizes, int n_in,
                              void* d_out, int out_size, void* d_ws, size_t ws_size,
                              hipStream_t stream) {
    const float* rs      = (const float*)d_in[0];
    const float* coords  = (const float*)d_in[1];
    const float* charges = (const float*)d_in[2];
    const float* W1      = (const float*)d_in[3];
    const float* b1      = (const float*)d_in[4];
    const float* W2      = (const float*)d_in[5];
    const float* b2      = (const float*)d_in[6];
    const float* W3      = (const float*)d_in[7];
    const float* b3      = (const float*)d_in[8];
    float* out = (float*)d_out;

    const int batch = in_sizes[0] / (N_EL * 3);   // 32768
    intx8* w1f8     = (intx8*)d_ws;                          // 368 KB
    float* dists    = (float*)((char*)d_ws + WS_DIST_OFF);   // 24 MB
    float* partials = (float*)((char*)d_ws + WS_PART_OFF);   // 32 MB

    prep_w1_kernel<<<N_PAIRS / 2, 256, 0, stream>>>(W1, w1f8);
    dist_kernel<<<batch / TB, 256, 0, stream>>>(rs, coords, dists);
    wfnet_gemm<<<batch / TB, BLOCK, 0, stream>>>(dists, w1f8, partials);
    wfnet_tail<<<batch / TB, BLOCK, 0, stream>>>(rs, coords, charges, partials,
                                                 b1, W2, b2, W3, b3, out);
}